// Round 4
// baseline (4532.767 us; speedup 1.0000x reference)
//
#include <hip/hip_runtime.h>
#include <hip/hip_bf16.h>
#include <hip/hip_cooperative_groups.h>

namespace cg = cooperative_groups;

typedef __hip_bfloat16 bf16;
typedef __bf16 bf16x8 __attribute__((ext_vector_type(8)));
typedef float f32x4 __attribute__((ext_vector_type(4)));

#define ROWS   32
#define HID    1024
#define PATH   256
#define NSTEP  50
#define P      1032   // LDS pitch (bf16) for inp(z) and th: 1024 + 8 -> uniform bank spread
#define SMEM_BYTES (2 * ROWS * P * 2)   // inp + th, bf16

__device__ __forceinline__ f32x4 mfma16(bf16x8 a, bf16x8 b, f32x4 c) {
    return __builtin_amdgcn_mfma_f32_16x16x32_bf16(a, b, c, 0, 0, 0);
}

__device__ __forceinline__ float tanh_fast(float x) {
    float e = __expf(2.0f * x);
    return 1.0f - 2.0f / (e + 1.0f);   // saturates, no NaN for finite x
}

__device__ __forceinline__ bf16x8 ldcvt8(const float* __restrict__ p) {
    f32x4 lo = *(const f32x4*)p;
    f32x4 hi = *(const f32x4*)(p + 4);
    bf16x8 r;
    #pragma unroll
    for (int j = 0; j < 4; j++) { r[j] = (__bf16)lo[j]; r[4 + j] = (__bf16)hi[j]; }
    return r;
}

// bf16x2 pack/unpack in a u32 (lo = elem0, hi = elem1)
__device__ __forceinline__ unsigned bfbits(float f) {
    __hip_bfloat16 h = __float2bfloat16(f);
    unsigned short u; __builtin_memcpy(&u, &h, 2);
    return (unsigned)u;
}
__device__ __forceinline__ unsigned bfpack2(float lo, float hi) {
    return bfbits(lo) | (bfbits(hi) << 16);
}
__device__ __forceinline__ float bflo(unsigned u) { return __uint_as_float(u << 16); }
__device__ __forceinline__ float bfhi(unsigned u) { return __uint_as_float(u & 0xffff0000u); }

// ---- pack f32 W[K][N] into bf16 MFMA B-fragment-linear layout ----
// fragment (kb, nb) = 1KB: lane l (lm=l&15, lq=l>>4) holds W[kb*32+lq*8+j][nb*16+lm]
__global__ void pack_frag(const float* __restrict__ src, bf16* __restrict__ dst, int N) {
    int kb = blockIdx.x, nb = blockIdx.y, l = threadIdx.x;
    int lm = l & 15, lq = l >> 4;
    bf16x8 v;
    #pragma unroll
    for (int j = 0; j < 8; j++)
        v[j] = __float2bfloat16(src[(size_t)(kb * 32 + lq * 8 + j) * N + nb * 16 + lm]);
    *(bf16x8*)(dst + ((size_t)(kb * gridDim.y + nb) * 64 + l) * 8) = v;
}

// preload one k-block's 4 weight fragments (issued by caller BEFORE the barrier
// that precedes the GEMM — global loads have no LDS dependency, so their latency
// overlaps the barrier wait / preceding VALU phase)
__device__ __forceinline__ void loadw4(const bf16* __restrict__ Wp, int k, int woff,
                                       bf16x8 (&w)[4]) {
    const bf16* wp = Wp + (size_t)k * 32768 + woff;
    #pragma unroll
    for (int nt = 0; nt < 4; nt++) w[nt] = *(const bf16x8*)(wp + nt * 512);
}

// ---- 32 x 64-col GEMM slice, software-pipelined, entry weights preloaded ----
// acc[2][4] += lds_A(32 rows, pitch P) @ Wp cols [wave*64, +64); KB k-blocks of 32.
// w[] enters holding k-block (rot); rolling in-place refill at ~1-kb distance,
// A-fragment ping-pong at 2-kb distance. Last pair peeled (no wasted wrap loads).
template<int KB>
__device__ __forceinline__ void gemm4h(const bf16* __restrict__ lds,
                                       const bf16* __restrict__ Wp,
                                       int wave, int lane, int rot,
                                       bf16x8 (&w)[4], f32x4 (&acc)[2][4]) {
    static_assert((KB & (KB - 1)) == 0, "KB must be a power of two");
    const int lm = lane & 15, lq = lane >> 4;
    const bf16* a0b = lds + lm * P + lq * 8;
    const bf16* a1b = a0b + 16 * P;
    const int woff = wave * 2048 + lane * 8;

    const int k0 = rot & (KB - 1);
    const int k1 = (rot + 1) & (KB - 1);
    bf16x8 a0A = *(const bf16x8*)(a0b + k0 * 32);
    bf16x8 a1A = *(const bf16x8*)(a1b + k0 * 32);
    bf16x8 a0B = *(const bf16x8*)(a0b + k1 * 32);
    bf16x8 a1B = *(const bf16x8*)(a1b + k1 * 32);

    #pragma unroll 1
    for (int kb = 0; kb < KB - 2; kb += 2) {
        const int kw1 = (kb + 1 + rot) & (KB - 1);
        const int kw2 = (kb + 2 + rot) & (KB - 1);
        const int kw3 = (kb + 3 + rot) & (KB - 1);
        const bf16* wp1 = Wp + (size_t)kw1 * 32768 + woff;
        const bf16* wp2 = Wp + (size_t)kw2 * 32768 + woff;
        // even half: consume (aA, w = kb); refill w <- kb+1, aA <- kb+2
        acc[0][0] = mfma16(a0A, w[0], acc[0][0]);
        acc[1][0] = mfma16(a1A, w[0], acc[1][0]);
        w[0] = *(const bf16x8*)(wp1);
        acc[0][1] = mfma16(a0A, w[1], acc[0][1]);
        acc[1][1] = mfma16(a1A, w[1], acc[1][1]);
        w[1] = *(const bf16x8*)(wp1 + 512);
        acc[0][2] = mfma16(a0A, w[2], acc[0][2]);
        acc[1][2] = mfma16(a1A, w[2], acc[1][2]);
        w[2] = *(const bf16x8*)(wp1 + 1024);
        acc[0][3] = mfma16(a0A, w[3], acc[0][3]);
        acc[1][3] = mfma16(a1A, w[3], acc[1][3]);
        w[3] = *(const bf16x8*)(wp1 + 1536);
        a0A = *(const bf16x8*)(a0b + kw2 * 32);
        a1A = *(const bf16x8*)(a1b + kw2 * 32);
        // odd half: consume (aB, w = kb+1); refill w <- kb+2, aB <- kb+3
        acc[0][0] = mfma16(a0B, w[0], acc[0][0]);
        acc[1][0] = mfma16(a1B, w[0], acc[1][0]);
        w[0] = *(const bf16x8*)(wp2);
        acc[0][1] = mfma16(a0B, w[1], acc[0][1]);
        acc[1][1] = mfma16(a1B, w[1], acc[1][1]);
        w[1] = *(const bf16x8*)(wp2 + 512);
        acc[0][2] = mfma16(a0B, w[2], acc[0][2]);
        acc[1][2] = mfma16(a1B, w[2], acc[1][2]);
        w[2] = *(const bf16x8*)(wp2 + 1024);
        acc[0][3] = mfma16(a0B, w[3], acc[0][3]);
        acc[1][3] = mfma16(a1B, w[3], acc[1][3]);
        w[3] = *(const bf16x8*)(wp2 + 1536);
        a0B = *(const bf16x8*)(a0b + kw3 * 32);
        a1B = *(const bf16x8*)(a1b + kw3 * 32);
    }
    // peeled last pair (kb = KB-2, KB-1): no wrap-around refills
    {
        const int kwl = (KB - 1 + rot) & (KB - 1);
        const bf16* wpl = Wp + (size_t)kwl * 32768 + woff;
        acc[0][0] = mfma16(a0A, w[0], acc[0][0]);
        acc[1][0] = mfma16(a1A, w[0], acc[1][0]);
        w[0] = *(const bf16x8*)(wpl);
        acc[0][1] = mfma16(a0A, w[1], acc[0][1]);
        acc[1][1] = mfma16(a1A, w[1], acc[1][1]);
        w[1] = *(const bf16x8*)(wpl + 512);
        acc[0][2] = mfma16(a0A, w[2], acc[0][2]);
        acc[1][2] = mfma16(a1A, w[2], acc[1][2]);
        w[2] = *(const bf16x8*)(wpl + 1024);
        acc[0][3] = mfma16(a0A, w[3], acc[0][3]);
        acc[1][3] = mfma16(a1A, w[3], acc[1][3]);
        w[3] = *(const bf16x8*)(wpl + 1536);
        acc[0][0] = mfma16(a0B, w[0], acc[0][0]);
        acc[1][0] = mfma16(a1B, w[0], acc[1][0]);
        acc[0][1] = mfma16(a0B, w[1], acc[0][1]);
        acc[1][1] = mfma16(a1B, w[1], acc[1][1]);
        acc[0][2] = mfma16(a0B, w[2], acc[0][2]);
        acc[1][2] = mfma16(a1B, w[2], acc[1][2]);
        acc[0][3] = mfma16(a0B, w[3], acc[0][3]);
        acc[1][3] = mfma16(a1B, w[3], acc[1][3]);
    }
}

// ---------------- persistent fused CDE kernel ----------------
// 256 wgs (1/CU), 1024 threads = 16 waves. Each wg owns 32 batch rows; z persists
// in f32 registers (MFMA C-layout). Wave w computes cols [64w,64w+64).
// Register file is saturated (64 VGPR + 64 AGPR = 128/lane at 16 waves/CU).
// KEY: one cooperative grid.sync() per step keeps all 256 blocks step-locked, so
// each XCD's 4 MiB L2 retains W1z+W2 (exactly 4 MiB) resident across all 50 steps
// -> weight loads are ~200-cy L2 hits, fully covered by the 1-kb refill distance.
// Without it, blocks drift across phases/steps and L2 capacity-misses (~7% of
// loads -> ~70 MB/step refetch) stall the 4-wave convoys at L3 latency.
__global__ __launch_bounds__(1024, 4) void cde_main(
    const float* __restrict__ x0,  const float* __restrict__ b_pe, const float* __restrict__ b_hi,
    const float* __restrict__ b1v, const float* __restrict__ b2v,  const float* __restrict__ b_ro,
    const bf16* __restrict__ WpeP, const bf16* __restrict__ WhiP,
    const bf16* __restrict__ W1zP, const bf16* __restrict__ W1uP,
    const bf16* __restrict__ W2P,  const bf16* __restrict__ WroP,
    float* __restrict__ out)
{
    extern __shared__ bf16 smem[];
    bf16* inp = smem;              // [32][P]  z staging (cols 0..1023); prologue: g staging
    bf16* th  = smem + ROWS * P;   // [32][P]  dt*tanh staging

    cg::grid_group grid = cg::this_grid();

    const int tid  = threadIdx.x;
    const int wave = tid >> 6;     // 0..15
    const int lane = tid & 63;
    const int lm   = lane & 15;
    const int lq   = lane >> 4;
    const int rot  = (blockIdx.x >> 3) & 31;   // per-CU spread within an XCD (r1-best)
    const int woff = wave * 2048 + lane * 8;
    const long row0 = (long)blockIdx.x * ROWS;

    f32x4 z[2][4];        // row = mt*16+lq*4+r, col = wave*64+nt*16+lm
    f32x4 g[2];           // col = wave*16+lm
    uint2 cu_pk[2][4];    // g @ W1u, packed bf16x2 pairs (r0,r1 | r2,r3)

    // ---- merged prologue: g = x0@W_pe + b_pe ; z = x0@W_hi + b_hi ----
    #pragma unroll
    for (int nt = 0; nt < 4; nt++) {
        float b = b_hi[wave * 64 + nt * 16 + lm];
        #pragma unroll
        for (int r = 0; r < 4; r++) { z[0][nt][r] = b; z[1][nt][r] = b; }
    }
    {
        float b = b_pe[wave * 16 + lm];
        #pragma unroll
        for (int r = 0; r < 4; r++) { g[0][r] = b; g[1][r] = b; }
    }
    for (int kb = 0; kb < HID / 32; kb++) {
        int kbr = kb + rot; if (kbr >= 32) kbr -= 32;
        bf16x8 a0 = ldcvt8(x0 + (row0 +      lm) * HID + kbr * 32 + lq * 8);
        bf16x8 a1 = ldcvt8(x0 + (row0 + 16 + lm) * HID + kbr * 32 + lq * 8);
        const bf16* wp = WhiP + (((size_t)kbr * 64 + wave * 4) * 64 + lane) * 8;
        #pragma unroll
        for (int nt = 0; nt < 4; nt++) {
            bf16x8 bb = *(const bf16x8*)(wp + nt * 512);
            z[0][nt] = mfma16(a0, bb, z[0][nt]);
            z[1][nt] = mfma16(a1, bb, z[1][nt]);
        }
        bf16x8 pb = *(const bf16x8*)(WpeP + (((size_t)kbr * 16 + wave) * 64 + lane) * 8);
        g[0] = mfma16(a0, pb, g[0]);
        g[1] = mfma16(a1, pb, g[1]);
    }

    // ---- c_u = g @ W1u (once), then compress to bf16 pairs ----
    #pragma unroll
    for (int mt = 0; mt < 2; mt++)
        #pragma unroll
        for (int r = 0; r < 4; r++)
            inp[(mt * 16 + lq * 4 + r) * P + wave * 16 + lm] = __float2bfloat16(g[mt][r]);
    __syncthreads();
    {
        f32x4 cu[2][4];
        #pragma unroll
        for (int mt = 0; mt < 2; mt++)
            #pragma unroll
            for (int nt = 0; nt < 4; nt++)
                #pragma unroll
                for (int r = 0; r < 4; r++) cu[mt][nt][r] = 0.0f;
        for (int kb = 0; kb < PATH / 32; kb++) {
            const bf16* wp = W1uP + (((size_t)kb * 64 + wave * 4) * 64 + lane) * 8;
            bf16x8 a0 = *(const bf16x8*)(inp + lm * P + kb * 32 + lq * 8);
            bf16x8 a1 = *(const bf16x8*)(inp + (16 + lm) * P + kb * 32 + lq * 8);
            #pragma unroll
            for (int nt = 0; nt < 4; nt++) {
                bf16x8 bb = *(const bf16x8*)(wp + nt * 512);
                cu[0][nt] = mfma16(a0, bb, cu[0][nt]);
                cu[1][nt] = mfma16(a1, bb, cu[1][nt]);
            }
        }
        #pragma unroll
        for (int mt = 0; mt < 2; mt++)
            #pragma unroll
            for (int nt = 0; nt < 4; nt++)
                cu_pk[mt][nt] = make_uint2(bfpack2(cu[mt][nt][0], cu[mt][nt][1]),
                                           bfpack2(cu[mt][nt][2], cu[mt][nt][3]));
    }
    __syncthreads();

    const float DT = 1.0f / (float)NSTEP;

    // hoisted biases, packed: lo = b1, hi = DT*b2 (bf16 rounding ~5e-5 abs, negligible)
    unsigned b12[4];
    #pragma unroll
    for (int nt = 0; nt < 4; nt++)
        b12[nt] = bfpack2(b1v[wave * 64 + nt * 16 + lm],
                          DT * b2v[wave * 64 + nt * 16 + lm]);

    bf16x8 wpre[4];
    loadw4(W1zP, rot, woff, wpre);     // first GEMM1's k-block, in flight early

    // ---- 50 fused steps, grid-locked ----
    for (int s = 0; s < NSTEP; s++) {
        float t = DT * (float)(s + 1);

        grid.sync();   // step-lock all blocks: keeps W1z+W2 (4 MiB) L2-resident per XCD

        // A-phase: refresh bf16 z staging
        #pragma unroll
        for (int mt = 0; mt < 2; mt++)
            #pragma unroll
            for (int nt = 0; nt < 4; nt++)
                #pragma unroll
                for (int r = 0; r < 4; r++)
                    inp[(mt * 16 + lq * 4 + r) * P + wave * 64 + nt * 16 + lm] =
                        __float2bfloat16(z[mt][nt][r]);
        __syncthreads();

        // B-phase: th = dt * tanh(z @ W1z + t*c_u + b1)
        {
            f32x4 acc[2][4];
            #pragma unroll
            for (int mt = 0; mt < 2; mt++)
                #pragma unroll
                for (int nt = 0; nt < 4; nt++) {
                    float b1 = bflo(b12[nt]);
                    unsigned px = cu_pk[mt][nt].x, py = cu_pk[mt][nt].y;
                    acc[mt][nt][0] = fmaf(t, bflo(px), b1);
                    acc[mt][nt][1] = fmaf(t, bfhi(px), b1);
                    acc[mt][nt][2] = fmaf(t, bflo(py), b1);
                    acc[mt][nt][3] = fmaf(t, bfhi(py), b1);
                }
            gemm4h<HID / 32>(inp, W1zP, wave, lane, rot, wpre, acc);
            loadw4(W2P, rot, woff, wpre);   // GEMM2 head loads hide under tanh+barrier
            #pragma unroll
            for (int mt = 0; mt < 2; mt++)
                #pragma unroll
                for (int nt = 0; nt < 4; nt++)
                    #pragma unroll
                    for (int r = 0; r < 4; r++)
                        th[(mt * 16 + lq * 4 + r) * P + wave * 64 + nt * 16 + lm] =
                            __float2bfloat16(DT * tanh_fast(acc[mt][nt][r]));
        }
        __syncthreads();

        // C-phase: z += dt*b2 ; z = (dt*h) @ W2 accumulated directly into z
        {
            #pragma unroll
            for (int mt = 0; mt < 2; mt++)
                #pragma unroll
                for (int nt = 0; nt < 4; nt++) {
                    float db = bfhi(b12[nt]);   // DT*b2
                    #pragma unroll
                    for (int r = 0; r < 4; r++) z[mt][nt][r] += db;
                }
            gemm4h<HID / 32>(th, W2P, wave, lane, rot, wpre, z);
            const bf16* nW = (s + 1 < NSTEP) ? W1zP : WroP;
            loadw4(nW, rot, woff, wpre);    // next step's GEMM1 / epilogue head loads
        }
        // no trailing block barrier needed: next iteration opens with grid.sync()
    }

    // ---- epilogue: out = z @ W_ro + b_ro (f32 store) ----
    #pragma unroll
    for (int mt = 0; mt < 2; mt++)
        #pragma unroll
        for (int nt = 0; nt < 4; nt++)
            #pragma unroll
            for (int r = 0; r < 4; r++)
                inp[(mt * 16 + lq * 4 + r) * P + wave * 64 + nt * 16 + lm] =
                    __float2bfloat16(z[mt][nt][r]);
    __syncthreads();
    {
        f32x4 acc[2][4];
        #pragma unroll
        for (int nt = 0; nt < 4; nt++) {
            float b = b_ro[wave * 64 + nt * 16 + lm];
            #pragma unroll
            for (int r = 0; r < 4; r++) { acc[0][nt][r] = b; acc[1][nt][r] = b; }
        }
        gemm4h<HID / 32>(inp, WroP, wave, lane, rot, wpre, acc);
        #pragma unroll
        for (int mt = 0; mt < 2; mt++)
            #pragma unroll
            for (int nt = 0; nt < 4; nt++)
                #pragma unroll
                for (int r = 0; r < 4; r++)
                    out[(row0 + mt * 16 + lq * 4 + r) * HID + wave * 64 + nt * 16 + lm] =
                        acc[mt][nt][r];
    }
}

extern "C" void kernel_launch(void* const* d_in, const int* in_sizes, int n_in,
                              void* d_out, int out_size, void* d_ws, size_t ws_size,
                              hipStream_t stream) {
    (void)in_sizes; (void)n_in; (void)out_size; (void)ws_size;
    const float* x0  = (const float*)d_in[0];
    const float* Wpe = (const float*)d_in[1];
    const float* bpe = (const float*)d_in[2];
    const float* Whi = (const float*)d_in[3];
    const float* bhi = (const float*)d_in[4];
    const float* W1  = (const float*)d_in[5];
    const float* b1  = (const float*)d_in[6];
    const float* W2  = (const float*)d_in[7];
    const float* b2  = (const float*)d_in[8];
    const float* Wro = (const float*)d_in[9];
    const float* bro = (const float*)d_in[10];

    bf16* ws   = (bf16*)d_ws;
    bf16* WpeP = ws;                          // 256*1024
    bf16* WhiP = WpeP + 256 * 1024;           // 1024*1024
    bf16* W1zP = WhiP + 1024 * 1024;          // 1024*1024 (W1 rows 0..1023)
    bf16* W1uP = W1zP + 1024 * 1024;          // 256*1024  (W1 rows 1024..1279)
    bf16* W2P  = W1uP + 256 * 1024;           // 1024*1024
    bf16* WroP = W2P  + 1024 * 1024;          // 1024*1024

    hipLaunchKernelGGL(pack_frag, dim3(1024 / 32, 256 / 16), dim3(64), 0, stream, Wpe, WpeP, 256);
    hipLaunchKernelGGL(pack_frag, dim3(1024 / 32, 1024 / 16), dim3(64), 0, stream, Whi, WhiP, 1024);
    hipLaunchKernelGGL(pack_frag, dim3(1024 / 32, 1024 / 16), dim3(64), 0, stream, W1, W1zP, 1024);
    hipLaunchKernelGGL(pack_frag, dim3(256 / 32, 1024 / 16), dim3(64), 0, stream,
                       W1 + (size_t)1024 * 1024, W1uP, 1024);
    hipLaunchKernelGGL(pack_frag, dim3(1024 / 32, 1024 / 16), dim3(64), 0, stream, W2, W2P, 1024);
    hipLaunchKernelGGL(pack_frag, dim3(1024 / 32, 1024 / 16), dim3(64), 0, stream, Wro, WroP, 1024);

    hipFuncSetAttribute((const void*)cde_main,
                        hipFuncAttributeMaxDynamicSharedMemorySize, SMEM_BYTES);

    const float* outp = (const float*)d_out;
    void* args[] = { (void*)&x0, (void*)&bpe, (void*)&bhi, (void*)&b1, (void*)&b2,
                     (void*)&bro, (void*)&WpeP, (void*)&WhiP, (void*)&W1zP, (void*)&W1uP,
                     (void*)&W2P, (void*)&WroP, (void*)&outp };
    hipLaunchCooperativeKernel((const void*)cde_main, dim3(8192 / ROWS), dim3(1024),
                               args, SMEM_BYTES, stream);
}

// Round 5
// 2943.223 us; speedup vs baseline: 1.5401x; 1.5401x over previous
//
#include <hip/hip_runtime.h>
#include <hip/hip_bf16.h>

typedef __hip_bfloat16 bf16;
typedef __bf16 bf16x8 __attribute__((ext_vector_type(8)));
typedef float f32x4 __attribute__((ext_vector_type(4)));

#define ROWS   32
#define HID    1024
#define PATH   256
#define NSTEP  50
#define P      1032   // LDS pitch (bf16) for inp(z) and th: 1024 + 8 -> uniform bank spread
#define SMEM_BYTES (2 * ROWS * P * 2)   // inp + th, bf16

__device__ __forceinline__ f32x4 mfma16(bf16x8 a, bf16x8 b, f32x4 c) {
    return __builtin_amdgcn_mfma_f32_16x16x32_bf16(a, b, c, 0, 0, 0);
}

__device__ __forceinline__ float tanh_fast(float x) {
    float e = __expf(2.0f * x);
    return 1.0f - 2.0f / (e + 1.0f);   // saturates, no NaN for finite x
}

__device__ __forceinline__ bf16x8 ldcvt8(const float* __restrict__ p) {
    f32x4 lo = *(const f32x4*)p;
    f32x4 hi = *(const f32x4*)(p + 4);
    bf16x8 r;
    #pragma unroll
    for (int j = 0; j < 4; j++) { r[j] = (__bf16)lo[j]; r[4 + j] = (__bf16)hi[j]; }
    return r;
}

// bf16x2 pack/unpack in a u32 (lo = elem0, hi = elem1)
__device__ __forceinline__ unsigned bfbits(float f) {
    __hip_bfloat16 h = __float2bfloat16(f);
    unsigned short u; __builtin_memcpy(&u, &h, 2);
    return (unsigned)u;
}
__device__ __forceinline__ unsigned bfpack2(float lo, float hi) {
    return bfbits(lo) | (bfbits(hi) << 16);
}
__device__ __forceinline__ float bflo(unsigned u) { return __uint_as_float(u << 16); }
__device__ __forceinline__ float bfhi(unsigned u) { return __uint_as_float(u & 0xffff0000u); }

// ---- pack f32 W[K][N] into bf16 MFMA B-fragment-linear layout ----
// fragment (kb, nb) = 1KB: lane l (lm=l&15, lq=l>>4) holds W[kb*32+lq*8+j][nb*16+lm]
__global__ void pack_frag(const float* __restrict__ src, bf16* __restrict__ dst, int N) {
    int kb = blockIdx.x, nb = blockIdx.y, l = threadIdx.x;
    int lm = l & 15, lq = l >> 4;
    bf16x8 v;
    #pragma unroll
    for (int j = 0; j < 8; j++)
        v[j] = __float2bfloat16(src[(size_t)(kb * 32 + lq * 8 + j) * N + nb * 16 + lm]);
    *(bf16x8*)(dst + ((size_t)(kb * gridDim.y + nb) * 64 + l) * 8) = v;
}

// preload one k-block's 4 weight fragments (issued by caller BEFORE the barrier
// that precedes the GEMM — global loads have no LDS dependency, so their latency
// overlaps the barrier wait / preceding VALU phase)
__device__ __forceinline__ void loadw4(const bf16* __restrict__ Wp, int k, int woff,
                                       bf16x8 (&w)[4]) {
    const bf16* wp = Wp + (size_t)k * 32768 + woff;
    #pragma unroll
    for (int nt = 0; nt < 4; nt++) w[nt] = *(const bf16x8*)(wp + nt * 512);
}

// ---- 32 x 64-col GEMM slice, 2-deep weight double-buffer ----
// acc[2][4] += lds_A(32 rows, pitch P) @ Wp cols [wave*64, +64); KB k-blocks of 32.
// wA enters holding k-block krot (preloaded across the preceding barrier).
// Even k-blocks consume wA (refill <- kb+2), odd consume wB (refill <- kb+3):
// each wave keeps ~8KB of global loads in flight (2x the single-buffer loop).
// A-fragments are single-buffered JIT LDS reads refilled mid-k-block (~80cy
// exposure, hidden by 4-wave TLP) - the 16 VGPRs saved pay for wB.
template<int KB>
__device__ __forceinline__ void gemm4d(const bf16* __restrict__ lds,
                                       const bf16* __restrict__ Wp,
                                       int wave, int lane, int krot,
                                       bf16x8 (&wA)[4], f32x4 (&acc)[2][4]) {
    static_assert((KB & (KB - 1)) == 0, "KB must be a power of two");
    const int lm = lane & 15, lq = lane >> 4;
    const bf16* a0b = lds + lm * P + lq * 8;
    const bf16* a1b = a0b + 16 * P;
    const int woff = wave * 2048 + lane * 8;

    bf16x8 wB[4];
    {
        const int k1 = (krot + 1) & (KB - 1);
        const bf16* wp = Wp + (size_t)k1 * 32768 + woff;
        #pragma unroll
        for (int nt = 0; nt < 4; nt++) wB[nt] = *(const bf16x8*)(wp + nt * 512);
    }
    const int k0 = krot & (KB - 1);
    bf16x8 a0 = *(const bf16x8*)(a0b + k0 * 32);
    bf16x8 a1 = *(const bf16x8*)(a1b + k0 * 32);

    #pragma unroll 1
    for (int kb = 0; kb < KB; kb += 2) {
        const int ka1 = (kb + 1 + krot) & (KB - 1);
        const int kw2 = (kb + 2 + krot) & (KB - 1);   // also next-even A kb
        const int kw3 = (kb + 3 + krot) & (KB - 1);
        const bf16* wp2 = Wp + (size_t)kw2 * 32768 + woff;
        const bf16* wp3 = Wp + (size_t)kw3 * 32768 + woff;
        // even half: consume a(kb), wA(kb)
        acc[0][0] = mfma16(a0, wA[0], acc[0][0]);
        acc[0][1] = mfma16(a0, wA[1], acc[0][1]);
        acc[0][2] = mfma16(a0, wA[2], acc[0][2]);
        acc[0][3] = mfma16(a0, wA[3], acc[0][3]);
        a0 = *(const bf16x8*)(a0b + ka1 * 32);
        acc[1][0] = mfma16(a1, wA[0], acc[1][0]);
        wA[0] = *(const bf16x8*)(wp2);
        acc[1][1] = mfma16(a1, wA[1], acc[1][1]);
        wA[1] = *(const bf16x8*)(wp2 + 512);
        acc[1][2] = mfma16(a1, wA[2], acc[1][2]);
        wA[2] = *(const bf16x8*)(wp2 + 1024);
        acc[1][3] = mfma16(a1, wA[3], acc[1][3]);
        wA[3] = *(const bf16x8*)(wp2 + 1536);
        a1 = *(const bf16x8*)(a1b + ka1 * 32);
        // odd half: consume a(kb+1), wB(kb+1)
        acc[0][0] = mfma16(a0, wB[0], acc[0][0]);
        acc[0][1] = mfma16(a0, wB[1], acc[0][1]);
        acc[0][2] = mfma16(a0, wB[2], acc[0][2]);
        acc[0][3] = mfma16(a0, wB[3], acc[0][3]);
        a0 = *(const bf16x8*)(a0b + kw2 * 32);
        acc[1][0] = mfma16(a1, wB[0], acc[1][0]);
        wB[0] = *(const bf16x8*)(wp3);
        acc[1][1] = mfma16(a1, wB[1], acc[1][1]);
        wB[1] = *(const bf16x8*)(wp3 + 512);
        acc[1][2] = mfma16(a1, wB[2], acc[1][2]);
        wB[2] = *(const bf16x8*)(wp3 + 1024);
        acc[1][3] = mfma16(a1, wB[3], acc[1][3]);
        wB[3] = *(const bf16x8*)(wp3 + 1536);
        a1 = *(const bf16x8*)(a1b + kw2 * 32);
    }
    // wrap refills ((KB)&31 etc.) re-read resident lines; values unused. Harmless.
}

// ---------------- persistent fused CDE kernel ----------------
// 256 wgs (1/CU), 1024 threads = 16 waves. Each wg owns 32 batch rows; z persists
// in f32 registers (MFMA C-layout). Wave w computes cols [64w,64w+64).
// Register file saturated (64 VGPR + 64 AGPR = 128/lane at 16 waves/CU):
//  - wB double-buffer paid for by dropping the A-fragment ping-pong.
//  - per-wave k-stagger (krot = rot + 2*wave) de-convoys the 16 waves' post-
//    barrier load bursts across the 32 k-blocks (weights stay L2-resident,
//    so per-wave sweep order is free).
__global__ __launch_bounds__(1024, 4) void cde_main(
    const float* __restrict__ x0,  const float* __restrict__ b_pe, const float* __restrict__ b_hi,
    const float* __restrict__ b1v, const float* __restrict__ b2v,  const float* __restrict__ b_ro,
    const bf16* __restrict__ WpeP, const bf16* __restrict__ WhiP,
    const bf16* __restrict__ W1zP, const bf16* __restrict__ W1uP,
    const bf16* __restrict__ W2P,  const bf16* __restrict__ WroP,
    float* __restrict__ out)
{
    extern __shared__ bf16 smem[];
    bf16* inp = smem;              // [32][P]  z staging (cols 0..1023); prologue: g staging
    bf16* th  = smem + ROWS * P;   // [32][P]  dt*tanh staging

    const int tid  = threadIdx.x;
    const int wave = tid >> 6;     // 0..15
    const int lane = tid & 63;
    const int lm   = lane & 15;
    const int lq   = lane >> 4;
    const int rot  = (blockIdx.x >> 3) & 31;       // per-CU spread within an XCD
    const int krot = (rot + wave * 2) & 31;        // + per-wave stagger
    const int woff = wave * 2048 + lane * 8;
    const long row0 = (long)blockIdx.x * ROWS;

    f32x4 z[2][4];        // row = mt*16+lq*4+r, col = wave*64+nt*16+lm
    f32x4 g[2];           // col = wave*16+lm
    uint2 cu_pk[2][4];    // g @ W1u, packed bf16x2 pairs (r0,r1 | r2,r3)

    // ---- merged prologue: g = x0@W_pe + b_pe ; z = x0@W_hi + b_hi ----
    #pragma unroll
    for (int nt = 0; nt < 4; nt++) {
        float b = b_hi[wave * 64 + nt * 16 + lm];
        #pragma unroll
        for (int r = 0; r < 4; r++) { z[0][nt][r] = b; z[1][nt][r] = b; }
    }
    {
        float b = b_pe[wave * 16 + lm];
        #pragma unroll
        for (int r = 0; r < 4; r++) { g[0][r] = b; g[1][r] = b; }
    }
    for (int kb = 0; kb < HID / 32; kb++) {
        int kbr = kb + krot; if (kbr >= 32) kbr -= 32;
        bf16x8 a0 = ldcvt8(x0 + (row0 +      lm) * HID + kbr * 32 + lq * 8);
        bf16x8 a1 = ldcvt8(x0 + (row0 + 16 + lm) * HID + kbr * 32 + lq * 8);
        const bf16* wp = WhiP + (((size_t)kbr * 64 + wave * 4) * 64 + lane) * 8;
        #pragma unroll
        for (int nt = 0; nt < 4; nt++) {
            bf16x8 bb = *(const bf16x8*)(wp + nt * 512);
            z[0][nt] = mfma16(a0, bb, z[0][nt]);
            z[1][nt] = mfma16(a1, bb, z[1][nt]);
        }
        bf16x8 pb = *(const bf16x8*)(WpeP + (((size_t)kbr * 16 + wave) * 64 + lane) * 8);
        g[0] = mfma16(a0, pb, g[0]);
        g[1] = mfma16(a1, pb, g[1]);
    }

    // ---- c_u = g @ W1u (once), then compress to bf16 pairs ----
    #pragma unroll
    for (int mt = 0; mt < 2; mt++)
        #pragma unroll
        for (int r = 0; r < 4; r++)
            inp[(mt * 16 + lq * 4 + r) * P + wave * 16 + lm] = __float2bfloat16(g[mt][r]);
    __syncthreads();
    {
        f32x4 cu[2][4];
        #pragma unroll
        for (int mt = 0; mt < 2; mt++)
            #pragma unroll
            for (int nt = 0; nt < 4; nt++)
                #pragma unroll
                for (int r = 0; r < 4; r++) cu[mt][nt][r] = 0.0f;
        for (int kb = 0; kb < PATH / 32; kb++) {
            const bf16* wp = W1uP + (((size_t)kb * 64 + wave * 4) * 64 + lane) * 8;
            bf16x8 a0 = *(const bf16x8*)(inp + lm * P + kb * 32 + lq * 8);
            bf16x8 a1 = *(const bf16x8*)(inp + (16 + lm) * P + kb * 32 + lq * 8);
            #pragma unroll
            for (int nt = 0; nt < 4; nt++) {
                bf16x8 bb = *(const bf16x8*)(wp + nt * 512);
                cu[0][nt] = mfma16(a0, bb, cu[0][nt]);
                cu[1][nt] = mfma16(a1, bb, cu[1][nt]);
            }
        }
        #pragma unroll
        for (int mt = 0; mt < 2; mt++)
            #pragma unroll
            for (int nt = 0; nt < 4; nt++)
                cu_pk[mt][nt] = make_uint2(bfpack2(cu[mt][nt][0], cu[mt][nt][1]),
                                           bfpack2(cu[mt][nt][2], cu[mt][nt][3]));
    }
    __syncthreads();

    const float DT = 1.0f / (float)NSTEP;

    // hoisted biases, packed: lo = b1, hi = DT*b2 (bf16 rounding ~5e-5 abs, negligible)
    unsigned b12[4];
    #pragma unroll
    for (int nt = 0; nt < 4; nt++)
        b12[nt] = bfpack2(b1v[wave * 64 + nt * 16 + lm],
                          DT * b2v[wave * 64 + nt * 16 + lm]);

    bf16x8 wpre[4];
    loadw4(W1zP, krot, woff, wpre);     // first GEMM1's k-block, in flight early

    // ---- 50 fused steps ----
    for (int s = 0; s < NSTEP; s++) {
        float t = DT * (float)(s + 1);

        // A-phase: refresh bf16 z staging
        #pragma unroll
        for (int mt = 0; mt < 2; mt++)
            #pragma unroll
            for (int nt = 0; nt < 4; nt++)
                #pragma unroll
                for (int r = 0; r < 4; r++)
                    inp[(mt * 16 + lq * 4 + r) * P + wave * 64 + nt * 16 + lm] =
                        __float2bfloat16(z[mt][nt][r]);
        __syncthreads();

        // B-phase: th = dt * tanh(z @ W1z + t*c_u + b1)
        {
            f32x4 acc[2][4];
            #pragma unroll
            for (int mt = 0; mt < 2; mt++)
                #pragma unroll
                for (int nt = 0; nt < 4; nt++) {
                    float b1 = bflo(b12[nt]);
                    unsigned px = cu_pk[mt][nt].x, py = cu_pk[mt][nt].y;
                    acc[mt][nt][0] = fmaf(t, bflo(px), b1);
                    acc[mt][nt][1] = fmaf(t, bfhi(px), b1);
                    acc[mt][nt][2] = fmaf(t, bflo(py), b1);
                    acc[mt][nt][3] = fmaf(t, bfhi(py), b1);
                }
            gemm4d<HID / 32>(inp, W1zP, wave, lane, krot, wpre, acc);
            loadw4(W2P, krot, woff, wpre);   // GEMM2 head loads hide under tanh+barrier
            #pragma unroll
            for (int mt = 0; mt < 2; mt++)
                #pragma unroll
                for (int nt = 0; nt < 4; nt++)
                    #pragma unroll
                    for (int r = 0; r < 4; r++)
                        th[(mt * 16 + lq * 4 + r) * P + wave * 64 + nt * 16 + lm] =
                            __float2bfloat16(DT * tanh_fast(acc[mt][nt][r]));
        }
        __syncthreads();

        // C-phase: z += dt*b2 ; z = (dt*h) @ W2 accumulated directly into z
        {
            #pragma unroll
            for (int mt = 0; mt < 2; mt++)
                #pragma unroll
                for (int nt = 0; nt < 4; nt++) {
                    float db = bfhi(b12[nt]);   // DT*b2
                    #pragma unroll
                    for (int r = 0; r < 4; r++) z[mt][nt][r] += db;
                }
            gemm4d<HID / 32>(th, W2P, wave, lane, krot, wpre, z);
            const bf16* nW = (s + 1 < NSTEP) ? W1zP : WroP;
            loadw4(nW, krot, woff, wpre);    // next step's GEMM1 / epilogue head loads
        }
        // no barrier: next A-write (inp) is safe — all waves passed the pre-C barrier
        // only after finishing their B-phase inp-reads (incl. wrap refills); th
        // hazards separated by the next loop's post-A barrier.
    }

    // ---- epilogue: out = z @ W_ro + b_ro (f32 store) ----
    #pragma unroll
    for (int mt = 0; mt < 2; mt++)
        #pragma unroll
        for (int nt = 0; nt < 4; nt++)
            #pragma unroll
            for (int r = 0; r < 4; r++)
                inp[(mt * 16 + lq * 4 + r) * P + wave * 64 + nt * 16 + lm] =
                    __float2bfloat16(z[mt][nt][r]);
    __syncthreads();
    {
        f32x4 acc[2][4];
        #pragma unroll
        for (int nt = 0; nt < 4; nt++) {
            float b = b_ro[wave * 64 + nt * 16 + lm];
            #pragma unroll
            for (int r = 0; r < 4; r++) { acc[0][nt][r] = b; acc[1][nt][r] = b; }
        }
        gemm4d<HID / 32>(inp, WroP, wave, lane, krot, wpre, acc);
        #pragma unroll
        for (int mt = 0; mt < 2; mt++)
            #pragma unroll
            for (int nt = 0; nt < 4; nt++)
                #pragma unroll
                for (int r = 0; r < 4; r++)
                    out[(row0 + mt * 16 + lq * 4 + r) * HID + wave * 64 + nt * 16 + lm] =
                        acc[mt][nt][r];
    }
}

extern "C" void kernel_launch(void* const* d_in, const int* in_sizes, int n_in,
                              void* d_out, int out_size, void* d_ws, size_t ws_size,
                              hipStream_t stream) {
    (void)in_sizes; (void)n_in; (void)out_size; (void)ws_size;
    const float* x0  = (const float*)d_in[0];
    const float* Wpe = (const float*)d_in[1];
    const float* bpe = (const float*)d_in[2];
    const float* Whi = (const float*)d_in[3];
    const float* bhi = (const float*)d_in[4];
    const float* W1  = (const float*)d_in[5];
    const float* b1  = (const float*)d_in[6];
    const float* W2  = (const float*)d_in[7];
    const float* b2  = (const float*)d_in[8];
    const float* Wro = (const float*)d_in[9];
    const float* bro = (const float*)d_in[10];

    bf16* ws   = (bf16*)d_ws;
    bf16* WpeP = ws;                          // 256*1024
    bf16* WhiP = WpeP + 256 * 1024;           // 1024*1024
    bf16* W1zP = WhiP + 1024 * 1024;          // 1024*1024 (W1 rows 0..1023)
    bf16* W1uP = W1zP + 1024 * 1024;          // 256*1024  (W1 rows 1024..1279)
    bf16* W2P  = W1uP + 256 * 1024;           // 1024*1024
    bf16* WroP = W2P  + 1024 * 1024;          // 1024*1024

    hipLaunchKernelGGL(pack_frag, dim3(1024 / 32, 256 / 16), dim3(64), 0, stream, Wpe, WpeP, 256);
    hipLaunchKernelGGL(pack_frag, dim3(1024 / 32, 1024 / 16), dim3(64), 0, stream, Whi, WhiP, 1024);
    hipLaunchKernelGGL(pack_frag, dim3(1024 / 32, 1024 / 16), dim3(64), 0, stream, W1, W1zP, 1024);
    hipLaunchKernelGGL(pack_frag, dim3(256 / 32, 1024 / 16), dim3(64), 0, stream,
                       W1 + (size_t)1024 * 1024, W1uP, 1024);
    hipLaunchKernelGGL(pack_frag, dim3(1024 / 32, 1024 / 16), dim3(64), 0, stream, W2, W2P, 1024);
    hipLaunchKernelGGL(pack_frag, dim3(1024 / 32, 1024 / 16), dim3(64), 0, stream, Wro, WroP, 1024);

    hipFuncSetAttribute((const void*)cde_main,
                        hipFuncAttributeMaxDynamicSharedMemorySize, SMEM_BYTES);
    hipLaunchKernelGGL(cde_main, dim3(8192 / ROWS), dim3(1024), SMEM_BYTES, stream,
                       x0, bpe, bhi, b1, b2, bro, WpeP, WhiP, W1zP, W1uP, W2P, WroP,
                       (float*)d_out);
}

// Round 6
// 2540.592 us; speedup vs baseline: 1.7841x; 1.1585x over previous
//
#include <hip/hip_runtime.h>
#include <hip/hip_bf16.h>

typedef __hip_bfloat16 bf16;
typedef __bf16 bf16x8 __attribute__((ext_vector_type(8)));
typedef float f32x4 __attribute__((ext_vector_type(4)));

#define ROWS   32
#define HID    1024
#define PATH   256
#define NSTEP  50
#define P      1032   // LDS pitch (bf16) for inp(z) and th: 1024 + 8 -> uniform bank spread
#define SMEM_BYTES (2 * ROWS * P * 2)   // inp + th, bf16

__device__ __forceinline__ f32x4 mfma16(bf16x8 a, bf16x8 b, f32x4 c) {
    return __builtin_amdgcn_mfma_f32_16x16x32_bf16(a, b, c, 0, 0, 0);
}

__device__ __forceinline__ float tanh_fast(float x) {
    float e = __expf(2.0f * x);
    return 1.0f - 2.0f / (e + 1.0f);   // saturates, no NaN for finite x
}

__device__ __forceinline__ bf16x8 ldcvt8(const float* __restrict__ p) {
    f32x4 lo = *(const f32x4*)p;
    f32x4 hi = *(const f32x4*)(p + 4);
    bf16x8 r;
    #pragma unroll
    for (int j = 0; j < 4; j++) { r[j] = (__bf16)lo[j]; r[4 + j] = (__bf16)hi[j]; }
    return r;
}

// bf16x2 pack/unpack in a u32 (lo = elem0, hi = elem1)
__device__ __forceinline__ unsigned bfbits(float f) {
    __hip_bfloat16 h = __float2bfloat16(f);
    unsigned short u; __builtin_memcpy(&u, &h, 2);
    return (unsigned)u;
}
__device__ __forceinline__ unsigned bfpack2(float lo, float hi) {
    return bfbits(lo) | (bfbits(hi) << 16);
}
__device__ __forceinline__ float bflo(unsigned u) { return __uint_as_float(u << 16); }
__device__ __forceinline__ float bfhi(unsigned u) { return __uint_as_float(u & 0xffff0000u); }

// ---- pack f32 W[K][N] into bf16 MFMA B-fragment-linear layout ----
// fragment (kb, nb) = 1KB: lane l (lm=l&15, lq=l>>4) holds W[kb*32+lq*8+j][nb*16+lm]
__global__ void pack_frag(const float* __restrict__ src, bf16* __restrict__ dst, int N) {
    int kb = blockIdx.x, nb = blockIdx.y, l = threadIdx.x;
    int lm = l & 15, lq = l >> 4;
    bf16x8 v;
    #pragma unroll
    for (int j = 0; j < 8; j++)
        v[j] = __float2bfloat16(src[(size_t)(kb * 32 + lq * 8 + j) * N + nb * 16 + lm]);
    *(bf16x8*)(dst + ((size_t)(kb * gridDim.y + nb) * 64 + l) * 8) = v;
}

// entry loads for one pass: k-blocks (krot, krot+1) x 2 col-fragments.
// issued a full pass (or tanh/store/barrier) before consumption.
__device__ __forceinline__ void loadw_entry(const bf16* __restrict__ Wp, int krot,
                                            int nboff, int lane, bf16x8 (&w)[4]) {
    const bf16* b = Wp + nboff + lane * 8;
    const int k1 = (krot + 1) & 31;
    const bf16* p0 = b + (size_t)krot * 32768;
    const bf16* p1 = b + (size_t)k1 * 32768;
    w[0] = *(const bf16x8*)(p0);
    w[1] = *(const bf16x8*)(p0 + 512);
    w[2] = *(const bf16x8*)(p1);
    w[3] = *(const bf16x8*)(p1 + 512);
}

__device__ __forceinline__ void init_acc(float t, float b1, uint2 cu, f32x4& c) {
    c[0] = fmaf(t, bflo(cu.x), b1);
    c[1] = fmaf(t, bfhi(cu.x), b1);
    c[2] = fmaf(t, bflo(cu.y), b1);
    c[3] = fmaf(t, bfhi(cu.y), b1);
}

// ---- 32-row x 32-col GEMM half-pass, 2-k-block-deep weight pipeline ----
// c{mt}{j} += lds_A(32 rows, pitch P) @ Wp cols [nboff/512*16, +32); KB k-blocks.
// wE enters holding k-blocks (krot, krot+1). Refill distance = 2 k-blocks
// (~2x the old gemm4p): wE[0..1] refilled at kb with kb+2's frags, consumed at
// kb+2 -> ~1.9k cy of cover vs ~950 before, clearing loaded L2 latency.
// A-fragments ping-pong at the same 2-block distance. Exact peel: zero wasted
// wrap loads (64 w-loads, 64 a-reads per pass = exact).
template<int KB>
__device__ __forceinline__ void gemm2p(const bf16* __restrict__ lds,
                                       const bf16* __restrict__ Wp,
                                       int lane, int krot, int nboff,
                                       bf16x8 (&wE)[4],
                                       f32x4& c00, f32x4& c01, f32x4& c10, f32x4& c11) {
    static_assert((KB & (KB - 1)) == 0, "KB must be a power of two");
    const int lm = lane & 15, lq = lane >> 4;
    const bf16* a0b = lds + lm * P + lq * 8;
    const bf16* a1b = a0b + 16 * P;
    const bf16* wb = Wp + nboff + lane * 8;

    const int k0 = krot & (KB - 1);
    const int k1 = (krot + 1) & (KB - 1);
    bf16x8 a0A = *(const bf16x8*)(a0b + k0 * 32);
    bf16x8 a1A = *(const bf16x8*)(a1b + k0 * 32);
    bf16x8 a0B = *(const bf16x8*)(a0b + k1 * 32);
    bf16x8 a1B = *(const bf16x8*)(a1b + k1 * 32);

    #pragma unroll 1
    for (int kb = 0; kb < KB - 2; kb += 2) {
        const int kw2 = (kb + 2 + krot) & (KB - 1);
        const int kw3 = (kb + 3 + krot) & (KB - 1);
        const bf16* wp2 = wb + (size_t)kw2 * 32768;
        const bf16* wp3 = wb + (size_t)kw3 * 32768;
        // even: consume (aA, wE[0..1] = kb); refill both <- kb+2
        c00 = mfma16(a0A, wE[0], c00);
        c10 = mfma16(a1A, wE[0], c10);
        wE[0] = *(const bf16x8*)(wp2);
        c01 = mfma16(a0A, wE[1], c01);
        c11 = mfma16(a1A, wE[1], c11);
        wE[1] = *(const bf16x8*)(wp2 + 512);
        a0A = *(const bf16x8*)(a0b + kw2 * 32);
        a1A = *(const bf16x8*)(a1b + kw2 * 32);
        // odd: consume (aB, wE[2..3] = kb+1); refill both <- kb+3
        c00 = mfma16(a0B, wE[2], c00);
        c10 = mfma16(a1B, wE[2], c10);
        wE[2] = *(const bf16x8*)(wp3);
        c01 = mfma16(a0B, wE[3], c01);
        c11 = mfma16(a1B, wE[3], c11);
        wE[3] = *(const bf16x8*)(wp3 + 512);
        a0B = *(const bf16x8*)(a0b + kw3 * 32);
        a1B = *(const bf16x8*)(a1b + kw3 * 32);
    }
    // peeled last pair: no refills
    c00 = mfma16(a0A, wE[0], c00);
    c10 = mfma16(a1A, wE[0], c10);
    c01 = mfma16(a0A, wE[1], c01);
    c11 = mfma16(a1A, wE[1], c11);
    c00 = mfma16(a0B, wE[2], c00);
    c10 = mfma16(a1B, wE[2], c10);
    c01 = mfma16(a0B, wE[3], c01);
    c11 = mfma16(a1B, wE[3], c11);
}

// ---------------- persistent fused CDE kernel ----------------
// 256 wgs (1/CU), 1024 threads = 16 waves. Each wg owns 32 batch rows; z persists
// in f32 registers (MFMA C-layout). Wave w computes cols [64w,64w+64).
// nt-SPLIT: each GEMM runs as two 32-col passes (acc 16 regs instead of 32);
// the freed 16 regs fund a second entry buffer wE2 so every pass's entry loads
// are issued >= one pass ahead, and intra-pass refills sit 2 k-blocks deep.
// VMEM issue is near-continuous across the whole step. k-order stays wg-uniform
// (rot per CU, r1-best; the r5 per-wave stagger blew up L2 -> reverted).
__global__ __launch_bounds__(1024, 4) void cde_main(
    const float* __restrict__ x0,  const float* __restrict__ b_pe, const float* __restrict__ b_hi,
    const float* __restrict__ b1v, const float* __restrict__ b2v,  const float* __restrict__ b_ro,
    const bf16* __restrict__ WpeP, const bf16* __restrict__ WhiP,
    const bf16* __restrict__ W1zP, const bf16* __restrict__ W1uP,
    const bf16* __restrict__ W2P,  const bf16* __restrict__ WroP,
    float* __restrict__ out)
{
    extern __shared__ bf16 smem[];
    bf16* inp = smem;              // [32][P]  z staging (cols 0..1023); prologue: g staging
    bf16* th  = smem + ROWS * P;   // [32][P]  dt*tanh staging

    const int tid  = threadIdx.x;
    const int wave = tid >> 6;     // 0..15
    const int lane = tid & 63;
    const int lm   = lane & 15;
    const int lq   = lane >> 4;
    const int rot  = (blockIdx.x >> 3) & 31;   // per-CU spread within an XCD (r1-best)
    const int nb0  = wave * 2048;              // pass0 col-fragment offset (elements)
    const int nb1  = wave * 2048 + 1024;       // pass1
    const long row0 = (long)blockIdx.x * ROWS;

    f32x4 z[2][4];        // row = mt*16+lq*4+r, col = wave*64+nt*16+lm
    f32x4 g[2];           // col = wave*16+lm
    uint2 cu_pk[2][4];    // g @ W1u, packed bf16x2 pairs (r0,r1 | r2,r3)

    // ---- merged prologue: g = x0@W_pe + b_pe ; z = x0@W_hi + b_hi ----
    #pragma unroll
    for (int nt = 0; nt < 4; nt++) {
        float b = b_hi[wave * 64 + nt * 16 + lm];
        #pragma unroll
        for (int r = 0; r < 4; r++) { z[0][nt][r] = b; z[1][nt][r] = b; }
    }
    {
        float b = b_pe[wave * 16 + lm];
        #pragma unroll
        for (int r = 0; r < 4; r++) { g[0][r] = b; g[1][r] = b; }
    }
    for (int kb = 0; kb < HID / 32; kb++) {
        int kbr = kb + rot; if (kbr >= 32) kbr -= 32;
        bf16x8 a0 = ldcvt8(x0 + (row0 +      lm) * HID + kbr * 32 + lq * 8);
        bf16x8 a1 = ldcvt8(x0 + (row0 + 16 + lm) * HID + kbr * 32 + lq * 8);
        const bf16* wp = WhiP + (((size_t)kbr * 64 + wave * 4) * 64 + lane) * 8;
        #pragma unroll
        for (int nt = 0; nt < 4; nt++) {
            bf16x8 bb = *(const bf16x8*)(wp + nt * 512);
            z[0][nt] = mfma16(a0, bb, z[0][nt]);
            z[1][nt] = mfma16(a1, bb, z[1][nt]);
        }
        bf16x8 pb = *(const bf16x8*)(WpeP + (((size_t)kbr * 16 + wave) * 64 + lane) * 8);
        g[0] = mfma16(a0, pb, g[0]);
        g[1] = mfma16(a1, pb, g[1]);
    }

    // ---- c_u = g @ W1u (once), then compress to bf16 pairs ----
    #pragma unroll
    for (int mt = 0; mt < 2; mt++)
        #pragma unroll
        for (int r = 0; r < 4; r++)
            inp[(mt * 16 + lq * 4 + r) * P + wave * 16 + lm] = __float2bfloat16(g[mt][r]);
    __syncthreads();
    {
        f32x4 cu[2][4];
        #pragma unroll
        for (int mt = 0; mt < 2; mt++)
            #pragma unroll
            for (int nt = 0; nt < 4; nt++)
                #pragma unroll
                for (int r = 0; r < 4; r++) cu[mt][nt][r] = 0.0f;
        for (int kb = 0; kb < PATH / 32; kb++) {
            const bf16* wp = W1uP + (((size_t)kb * 64 + wave * 4) * 64 + lane) * 8;
            bf16x8 a0 = *(const bf16x8*)(inp + lm * P + kb * 32 + lq * 8);
            bf16x8 a1 = *(const bf16x8*)(inp + (16 + lm) * P + kb * 32 + lq * 8);
            #pragma unroll
            for (int nt = 0; nt < 4; nt++) {
                bf16x8 bb = *(const bf16x8*)(wp + nt * 512);
                cu[0][nt] = mfma16(a0, bb, cu[0][nt]);
                cu[1][nt] = mfma16(a1, bb, cu[1][nt]);
            }
        }
        #pragma unroll
        for (int mt = 0; mt < 2; mt++)
            #pragma unroll
            for (int nt = 0; nt < 4; nt++)
                cu_pk[mt][nt] = make_uint2(bfpack2(cu[mt][nt][0], cu[mt][nt][1]),
                                           bfpack2(cu[mt][nt][2], cu[mt][nt][3]));
    }
    __syncthreads();

    const float DT = 1.0f / (float)NSTEP;

    // hoisted biases, packed: lo = b1, hi = DT*b2 (bf16 rounding ~5e-5 abs, negligible)
    unsigned b12[4];
    #pragma unroll
    for (int nt = 0; nt < 4; nt++)
        b12[nt] = bfpack2(b1v[wave * 64 + nt * 16 + lm],
                          DT * b2v[wave * 64 + nt * 16 + lm]);

    bf16x8 wE[4], wE2[4];
    loadw_entry(W1zP, rot, nb0, lane, wE);     // first B-pass0 entries, in flight early

    // ---- 50 fused steps ----
    for (int s = 0; s < NSTEP; s++) {
        float t = DT * (float)(s + 1);

        // A-phase: refresh bf16 z staging
        #pragma unroll
        for (int mt = 0; mt < 2; mt++)
            #pragma unroll
            for (int nt = 0; nt < 4; nt++)
                #pragma unroll
                for (int r = 0; r < 4; r++)
                    inp[(mt * 16 + lq * 4 + r) * P + wave * 64 + nt * 16 + lm] =
                        __float2bfloat16(z[mt][nt][r]);
        __syncthreads();

        loadw_entry(W1zP, rot, nb1, lane, wE2);    // pass1 entries: covered by pass0

        // B pass0: cols [64w, 64w+32)
        {
            f32x4 c00, c01, c10, c11;
            init_acc(t, bflo(b12[0]), cu_pk[0][0], c00);
            init_acc(t, bflo(b12[1]), cu_pk[0][1], c01);
            init_acc(t, bflo(b12[0]), cu_pk[1][0], c10);
            init_acc(t, bflo(b12[1]), cu_pk[1][1], c11);
            gemm2p<HID / 32>(inp, W1zP, lane, rot, nb0, wE, c00, c01, c10, c11);
            bf16* tb = th + wave * 64 + lm;
            #pragma unroll
            for (int r = 0; r < 4; r++) {
                tb[(lq * 4 + r) * P]           = __float2bfloat16(DT * tanh_fast(c00[r]));
                tb[(lq * 4 + r) * P + 16]      = __float2bfloat16(DT * tanh_fast(c01[r]));
                tb[(16 + lq * 4 + r) * P]      = __float2bfloat16(DT * tanh_fast(c10[r]));
                tb[(16 + lq * 4 + r) * P + 16] = __float2bfloat16(DT * tanh_fast(c11[r]));
            }
        }
        // B pass1: cols [64w+32, 64w+64)
        {
            f32x4 c00, c01, c10, c11;
            init_acc(t, bflo(b12[2]), cu_pk[0][2], c00);
            init_acc(t, bflo(b12[3]), cu_pk[0][3], c01);
            init_acc(t, bflo(b12[2]), cu_pk[1][2], c10);
            init_acc(t, bflo(b12[3]), cu_pk[1][3], c11);
            gemm2p<HID / 32>(inp, W1zP, lane, rot, nb1, wE2, c00, c01, c10, c11);
            loadw_entry(W2P, rot, nb0, lane, wE);  // C-pass0 entries: covered by tanh+barrier
            bf16* tb = th + wave * 64 + 32 + lm;
            #pragma unroll
            for (int r = 0; r < 4; r++) {
                tb[(lq * 4 + r) * P]           = __float2bfloat16(DT * tanh_fast(c00[r]));
                tb[(lq * 4 + r) * P + 16]      = __float2bfloat16(DT * tanh_fast(c01[r]));
                tb[(16 + lq * 4 + r) * P]      = __float2bfloat16(DT * tanh_fast(c10[r]));
                tb[(16 + lq * 4 + r) * P + 16] = __float2bfloat16(DT * tanh_fast(c11[r]));
            }
        }
        __syncthreads();

        loadw_entry(W2P, rot, nb1, lane, wE2);     // C-pass1 entries: covered by pass0

        // C pass0: z cols 0-1 += dt*b2 ; accumulate (dt*h) @ W2 directly into z
        {
            float d0 = bfhi(b12[0]), d1 = bfhi(b12[1]);
            #pragma unroll
            for (int r = 0; r < 4; r++) {
                z[0][0][r] += d0; z[0][1][r] += d1;
                z[1][0][r] += d0; z[1][1][r] += d1;
            }
            gemm2p<HID / 32>(th, W2P, lane, rot, nb0, wE, z[0][0], z[0][1], z[1][0], z[1][1]);
        }
        // C pass1: z cols 2-3
        {
            float d2 = bfhi(b12[2]), d3 = bfhi(b12[3]);
            #pragma unroll
            for (int r = 0; r < 4; r++) {
                z[0][2][r] += d2; z[0][3][r] += d3;
                z[1][2][r] += d2; z[1][3][r] += d3;
            }
            gemm2p<HID / 32>(th, W2P, lane, rot, nb1, wE2, z[0][2], z[0][3], z[1][2], z[1][3]);
            const bf16* nW = (s + 1 < NSTEP) ? W1zP : WroP;
            loadw_entry(nW, rot, nb0, lane, wE);   // next B-pass0 / epilogue: covered by A+barrier
        }
        // no barrier: next A-write (inp) is safe — all waves passed the pre-C barrier
        // only after finishing their B-phase inp-reads; th hazards separated by the
        // next loop's post-A barrier.
    }

    // ---- epilogue: out = z @ W_ro + b_ro (f32 store), two passes ----
    #pragma unroll
    for (int mt = 0; mt < 2; mt++)
        #pragma unroll
        for (int nt = 0; nt < 4; nt++)
            #pragma unroll
            for (int r = 0; r < 4; r++)
                inp[(mt * 16 + lq * 4 + r) * P + wave * 64 + nt * 16 + lm] =
                    __float2bfloat16(z[mt][nt][r]);
    __syncthreads();
    loadw_entry(WroP, rot, nb1, lane, wE2);
    {
        f32x4 c00, c01, c10, c11;
        float br0 = b_ro[wave * 64 + lm], br1 = b_ro[wave * 64 + 16 + lm];
        #pragma unroll
        for (int r = 0; r < 4; r++) { c00[r] = br0; c01[r] = br1; c10[r] = br0; c11[r] = br1; }
        gemm2p<HID / 32>(inp, WroP, lane, rot, nb0, wE, c00, c01, c10, c11);
        #pragma unroll
        for (int r = 0; r < 4; r++) {
            out[(row0 + lq * 4 + r) * HID + wave * 64 + lm]           = c00[r];
            out[(row0 + lq * 4 + r) * HID + wave * 64 + 16 + lm]      = c01[r];
            out[(row0 + 16 + lq * 4 + r) * HID + wave * 64 + lm]      = c10[r];
            out[(row0 + 16 + lq * 4 + r) * HID + wave * 64 + 16 + lm] = c11[r];
        }
    }
    {
        f32x4 c00, c01, c10, c11;
        float br2 = b_ro[wave * 64 + 32 + lm], br3 = b_ro[wave * 64 + 48 + lm];
        #pragma unroll
        for (int r = 0; r < 4; r++) { c00[r] = br2; c01[r] = br3; c10[r] = br2; c11[r] = br3; }
        gemm2p<HID / 32>(inp, WroP, lane, rot, nb1, wE2, c00, c01, c10, c11);
        #pragma unroll
        for (int r = 0; r < 4; r++) {
            out[(row0 + lq * 4 + r) * HID + wave * 64 + 32 + lm]      = c00[r];
            out[(row0 + lq * 4 + r) * HID + wave * 64 + 48 + lm]      = c01[r];
            out[(row0 + 16 + lq * 4 + r) * HID + wave * 64 + 32 + lm] = c10[r];
            out[(row0 + 16 + lq * 4 + r) * HID + wave * 64 + 48 + lm] = c11[r];
        }
    }
}

extern "C" void kernel_launch(void* const* d_in, const int* in_sizes, int n_in,
                              void* d_out, int out_size, void* d_ws, size_t ws_size,
                              hipStream_t stream) {
    (void)in_sizes; (void)n_in; (void)out_size; (void)ws_size;
    const float* x0  = (const float*)d_in[0];
    const float* Wpe = (const float*)d_in[1];
    const float* bpe = (const float*)d_in[2];
    const float* Whi = (const float*)d_in[3];
    const float* bhi = (const float*)d_in[4];
    const float* W1  = (const float*)d_in[5];
    const float* b1  = (const float*)d_in[6];
    const float* W2  = (const float*)d_in[7];
    const float* b2  = (const float*)d_in[8];
    const float* Wro = (const float*)d_in[9];
    const float* bro = (const float*)d_in[10];

    bf16* ws   = (bf16*)d_ws;
    bf16* WpeP = ws;                          // 256*1024
    bf16* WhiP = WpeP + 256 * 1024;           // 1024*1024
    bf16* W1zP = WhiP + 1024 * 1024;          // 1024*1024 (W1 rows 0..1023)
    bf16* W1uP = W1zP + 1024 * 1024;          // 256*1024  (W1 rows 1024..1279)
    bf16* W2P  = W1uP + 256 * 1024;           // 1024*1024
    bf16* WroP = W2P  + 1024 * 1024;          // 1024*1024

    hipLaunchKernelGGL(pack_frag, dim3(1024 / 32, 256 / 16), dim3(64), 0, stream, Wpe, WpeP, 256);
    hipLaunchKernelGGL(pack_frag, dim3(1024 / 32, 1024 / 16), dim3(64), 0, stream, Whi, WhiP, 1024);
    hipLaunchKernelGGL(pack_frag, dim3(1024 / 32, 1024 / 16), dim3(64), 0, stream, W1, W1zP, 1024);
    hipLaunchKernelGGL(pack_frag, dim3(256 / 32, 1024 / 16), dim3(64), 0, stream,
                       W1 + (size_t)1024 * 1024, W1uP, 1024);
    hipLaunchKernelGGL(pack_frag, dim3(1024 / 32, 1024 / 16), dim3(64), 0, stream, W2, W2P, 1024);
    hipLaunchKernelGGL(pack_frag, dim3(1024 / 32, 1024 / 16), dim3(64), 0, stream, Wro, WroP, 1024);

    hipFuncSetAttribute((const void*)cde_main,
                        hipFuncAttributeMaxDynamicSharedMemorySize, SMEM_BYTES);
    hipLaunchKernelGGL(cde_main, dim3(8192 / ROWS), dim3(1024), SMEM_BYTES, stream,
                       x0, bpe, bhi, b1, b2, bro, WpeP, WhiP, W1zP, W1uP, W2P, WroP,
                       (float*)d_out);
}